// Round 1
// baseline (713.110 us; speedup 1.0000x reference)
//
#include <hip/hip_runtime.h>
#include <stdint.h>

// ---------------------------------------------------------------------------
// ANI-style species-routed MLP, fused, f16 MFMA (gfx950).
// Block = 1 atom x 64 molecules (rows). All rows share species[atom] -> plain
// GEMM per block. Layers 384->256->192->160->1, CELU(0.1) after each, then
// atom-pool via atomicAdd.
// Weights are re-packed each launch (d_ws re-poisoned) into MFMA-fragment
// order so K-loop LDS reads are linear ds_read_b128.
// mfma(W_frag, act_frag) computes (act*W)^T: for 32x32x16 the A and B lane
// mappings coincide (outer = lane&31, k = (lane>>5)*8+j), so packed W serves
// directly as the A operand and the transposed C makes the epilogue write
// 4 consecutive output channels per ds_write_b64.
// ---------------------------------------------------------------------------

typedef _Float16 f16;
typedef _Float16 f16x8 __attribute__((ext_vector_type(8)));
typedef _Float16 f16x4 __attribute__((ext_vector_type(4)));
typedef float f32x16 __attribute__((ext_vector_type(16)));

static constexpr int BMOL = 1024;   // molecules
static constexpr int NATOM = 256;   // atoms
static constexpr int TB = 64;       // rows (molecules) per block

// packed-weight offsets in f16 units (per layer, 4 species each)
// L0: K=384 N=256 NT=8  -> 98304/species
// L1: K=256 N=192 NT=6  -> 49152/species
// L2: K=192 N=160 pad192 NT=6 -> 36864/species (zero-padded cols 160..191)
// L3: 160x1 linear
static constexpr size_t PK0 = 0;
static constexpr size_t PK1 = PK0 + 4 * (size_t)98304;   // 393216
static constexpr size_t PK2 = PK1 + 4 * (size_t)49152;   // 589824
static constexpr size_t PK3 = PK2 + 4 * (size_t)36864;   // 737280
// total 737920 f16 = 1.44 MB of d_ws

// LDS layout (bytes). act strides chosen so stride/16 is ODD -> the 32 lanes
// of a b128 fragment read hit distinct 16B slots (conflict-free).
static constexpr int OFF_ACT0 = 0;      // 64 x 264 f16 = 33792  (act2 reuses: 64x200=25600)
static constexpr int OFF_ACT1 = 33792;  // 64 x 200 f16 = 25600 -> ends 59392
static constexpr int OFF_XBUF = 33792;  // L0 only: 2 x (64 x 40 f16 = 5120) inside act1 region
static constexpr int OFF_WBUF = 59392;  // 2 x 8192 -> ends 75776
static constexpr int OFF_BIAS = 75776;  // 256 f32 = 1024
static constexpr int OFF_W3   = 76800;  // 160 f16 = 320
static constexpr int SMEM_BYTES = 77184;

__device__ __forceinline__ float celu_f(float x) {
    // celu(x, 0.1) = max(x,0) + min(0, 0.1*(exp(x/0.1)-1))
    float e = __expf(x * 10.0f);
    return fmaxf(x, 0.0f) + fminf(0.0f, 0.1f * (e - 1.0f));
}

// ---------------- prep: pack weights to fragment order ----------------
__global__ void pack_weights(const float* __restrict__ W0, const float* __restrict__ W1,
                             const float* __restrict__ W2, const float* __restrict__ W3,
                             f16* __restrict__ wp)
{
    const int layer = blockIdx.y;
    int K, Nreal, NT, E; const float* W; size_t base;
    if (layer == 0)      { K = 384; Nreal = 256; NT = 8; E = 98304; W = W0; base = PK0; }
    else if (layer == 1) { K = 256; Nreal = 192; NT = 6; E = 49152; W = W1; base = PK1; }
    else if (layer == 2) { K = 192; Nreal = 160; NT = 6; E = 36864; W = W2; base = PK2; }
    else                 { K = 160; Nreal = 1;   NT = 1; E = 160;   W = W3; base = PK3; }
    const int total = 4 * E;
    for (int p = blockIdx.x * blockDim.x + threadIdx.x; p < total; p += gridDim.x * blockDim.x) {
        const int s = p / E, q = p - s * E;
        if (layer == 3) { wp[base + p] = (f16)W[s * 160 + q]; continue; }
        // flat = ((ks*NT + nt)*64 + l)*8 + j
        const int j = q & 7, l = (q >> 3) & 63, r = q >> 9;
        const int nt = r % NT, ks = r / NT;
        const int k = ks * 16 + ((l >> 5) << 3) + j;
        const int o = nt * 32 + (l & 31);
        const float v = (o < Nreal) ? W[(s * K + k) * Nreal + o] : 0.0f;
        wp[base + p] = (f16)v;
    }
}

// ---------------- helpers ----------------
__device__ __forceinline__ void loadx8(float* d, const float* p) {
    float4 u = *(const float4*)p;
    float4 v = *(const float4*)(p + 4);
    d[0]=u.x; d[1]=u.y; d[2]=u.z; d[3]=u.w; d[4]=v.x; d[5]=v.y; d[6]=v.z; d[7]=v.w;
}
__device__ __forceinline__ void writex8(char* xb, int row, int kq, const float* v) {
    f16x8 h;
#pragma unroll
    for (int i = 0; i < 8; i++) h[i] = (f16)v[i];
    *(f16x8*)(xb + row * 80 + kq * 2) = h;   // stride 40 f16 = 80 B (slot stride 5, odd)
}

template<int NT>
__device__ __forceinline__ void wload(uint2* wr, const f16* wsrc, int ks, int t) {
    const uint2* p = (const uint2*)wsrc + (size_t)ks * NT * 128 + t;
#pragma unroll
    for (int i = 0; i < NT / 2; i++) wr[i] = p[i * 256];
}
template<int NT>
__device__ __forceinline__ void wwrite(const uint2* wr, char* dst, int t) {
    uint2* p = (uint2*)dst + t;
#pragma unroll
    for (int i = 0; i < NT / 2; i++) p[i * 256] = wr[i];
}

template<int NT>
__device__ __forceinline__ void mfma_step(const char* actbase, int strideB, int kByteOff,
                                          const char* wslab, int l, int w, f32x16 acc[2][2]) {
    const int lo = l & 31, hi = l >> 5;
    f16x8 af0 = *(const f16x8*)(actbase + lo * strideB + kByteOff + hi * 16);
    f16x8 af1 = *(const f16x8*)(actbase + (32 + lo) * strideB + kByteOff + hi * 16);
#pragma unroll
    for (int ni = 0; ni < 2; ni++) {
        const int nt = w + ni * 4;
        if (nt < NT) {
            f16x8 wf = *(const f16x8*)(wslab + (nt * 64 + l) * 16);
            acc[ni][0] = __builtin_amdgcn_mfma_f32_32x32x16_f16(wf, af0, acc[ni][0], 0, 0, 0);
            acc[ni][1] = __builtin_amdgcn_mfma_f32_32x32x16_f16(wf, af1, acc[ni][1], 0, 0, 0);
        }
    }
}

template<int NT>
__device__ __forceinline__ void epilogue(f32x16 acc[2][2], char* actout, int strideB,
                                         const float* biasL, int l, int w) {
    const int lo = l & 31, hi = l >> 5;
#pragma unroll
    for (int ni = 0; ni < 2; ni++) {
        const int nt = w + ni * 4;
        if (nt >= NT) continue;
#pragma unroll
        for (int mi = 0; mi < 2; mi++) {
            const int row = mi * 32 + lo;
#pragma unroll
            for (int q = 0; q < 4; q++) {
                const int o = nt * 32 + q * 8 + hi * 4;   // C row = (reg&3)+8*(reg>>2)+4*hi
                float4 bv = *(const float4*)(biasL + o);
                const float* bp = (const float*)&bv;
                f16x4 hv;
#pragma unroll
                for (int d = 0; d < 4; d++) {
                    float v = acc[ni][mi][q * 4 + d] + bp[d];
                    hv[d] = (f16)celu_f(v);
                }
                *(f16x4*)(actout + row * strideB + o * 2) = hv;
            }
        }
    }
}

template<int KS, int NT>
__device__ __forceinline__ void gemm_lds(const char* actin, int sin, char* actout, int sout,
                                         const f16* wsrc, const float* bsrc, int Nreal, int sp,
                                         char* wbuf, float* biasL, int t, int l, int w,
                                         f32x16 acc[2][2]) {
    for (int o = t; o < NT * 32; o += 256) biasL[o] = (o < Nreal) ? bsrc[sp * Nreal + o] : 0.0f;
#pragma unroll
    for (int ni = 0; ni < 2; ni++)
#pragma unroll
        for (int mi = 0; mi < 2; mi++)
#pragma unroll
            for (int e = 0; e < 16; e++) acc[ni][mi][e] = 0.0f;

    uint2 wreg[4];
    wload<NT>(wreg, wsrc, 0, t);
    wwrite<NT>(wreg, wbuf, t);
    __syncthreads();
    for (int ks = 0; ks < KS; ks++) {
        if (ks + 1 < KS) wload<NT>(wreg, wsrc, ks + 1, t);
        mfma_step<NT>(actin, sin, ks * 32, wbuf + (ks & 1) * (NT * 1024), l, w, acc);
        if (ks + 1 < KS) wwrite<NT>(wreg, wbuf + ((ks + 1) & 1) * (NT * 1024), t);
        __syncthreads();
    }
    epilogue<NT>(acc, actout, sout, biasL, l, w);
    __syncthreads();
}

// ---------------- main fused kernel ----------------
__global__ void __launch_bounds__(256, 2)
ani_kernel(const float* __restrict__ X, const int* __restrict__ species,
           const float* __restrict__ B0, const float* __restrict__ B1,
           const float* __restrict__ B2, const float* __restrict__ B3,
           const f16* __restrict__ wp, float* __restrict__ out)
{
    __shared__ __align__(16) char smem[SMEM_BYTES];
    char* act0 = smem + OFF_ACT0;   // stride 528 B (264 f16)
    char* act1 = smem + OFF_ACT1;   // stride 400 B (200 f16)
    char* act2 = smem + OFF_ACT0;   // stride 400 B, reuses act0 region
    char* xbuf = smem + OFF_XBUF;   // 2 x 5120 B
    char* wbuf = smem + OFF_WBUF;   // 2 x 8192 B
    float* biasL = (float*)(smem + OFF_BIAS);
    f16* w3l = (f16*)(smem + OFF_W3);

    const int t = threadIdx.x, l = t & 63, w = t >> 6;
    const int atom = blockIdx.y;
    const long brow0 = (long)blockIdx.x * TB;
    const int sp = species[atom];

    if (t < 160) w3l[t] = wp[PK3 + sp * 160 + t];

    f32x16 acc[2][2];

    // ======== Layer 0: 384 -> 256 (K streamed from HBM) ========
    {
        constexpr int NT = 8, KS = 24, NC = 12;
        const f16* wsrc = wp + PK0 + (size_t)sp * 98304;
        if (t < 256) biasL[t] = B0[sp * 256 + t];

        const int xrow_i = t >> 2, kq = (t & 3) * 8;
        const float* xrow = X + ((brow0 + xrow_i) * (long)NATOM + atom) * 384 + kq;

        float xr[2][8];
        uint2 wreg[4];
#pragma unroll
        for (int ni = 0; ni < 2; ni++)
#pragma unroll
            for (int mi = 0; mi < 2; mi++)
#pragma unroll
                for (int e = 0; e < 16; e++) acc[ni][mi][e] = 0.0f;

        loadx8(xr[0], xrow);
        loadx8(xr[1], xrow + 32);
        wload<NT>(wreg, wsrc, 0, t);
        writex8(xbuf, xrow_i, kq, xr[0]);
        wwrite<NT>(wreg, wbuf, t);
        __syncthreads();

        for (int ks = 0; ks < KS; ks++) {
            const int c = ks >> 1, h = ks & 1;
            if (ks + 1 < KS) wload<NT>(wreg, wsrc, ks + 1, t);
            mfma_step<NT>(xbuf + (c & 1) * 5120, 80, h * 32, wbuf + (ks & 1) * 8192, l, w, acc);
            if (ks + 1 < KS) wwrite<NT>(wreg, wbuf + ((ks + 1) & 1) * 8192, t);
            if (h == 1) {
                if (c + 1 < NC) writex8(xbuf + ((c + 1) & 1) * 5120, xrow_i, kq, xr[(c + 1) & 1]);
                if (c + 2 < NC) loadx8(xr[c & 1], xrow + (c + 2) * 32);
            }
            __syncthreads();
        }
        epilogue<NT>(acc, act0, 528, biasL, l, w);
        __syncthreads();
    }

    // ======== Layer 1: 256 -> 192 ========
    gemm_lds<16, 6>(act0, 528, act1, 400, wp + PK1 + (size_t)sp * 49152, B1, 192, sp,
                    wbuf, biasL, t, l, w, acc);

    // ======== Layer 2: 192 -> 160 (padded to 192) ========
    gemm_lds<12, 6>(act1, 400, act2, 400, wp + PK2 + (size_t)sp * 36864, B2, 160, sp,
                    wbuf, biasL, t, l, w, acc);

    // ======== Layer 3: 160 -> 1, CELU, pool over atoms ========
    {
        const int row = t >> 2, part = t & 3;
        const char* arow = act2 + row * 400 + part * 80;
        const f16* wrow = w3l + part * 40;
        float sum = 0.0f;
#pragma unroll
        for (int g = 0; g < 5; g++) {
            f16x8 a = *(const f16x8*)(arow + g * 16);
            f16x8 wv = *(const f16x8*)(wrow + g * 8);
#pragma unroll
            for (int e = 0; e < 8; e++) sum += (float)a[e] * (float)wv[e];
        }
        sum += __shfl_xor(sum, 1, 64);
        sum += __shfl_xor(sum, 2, 64);
        if (part == 0) {
            float y = celu_f(sum + B3[sp]);
            atomicAdd(out + brow0 + row, y);
        }
    }
}

// ---------------- launch ----------------
extern "C" void kernel_launch(void* const* d_in, const int* in_sizes, int n_in,
                              void* d_out, int out_size, void* d_ws, size_t ws_size,
                              hipStream_t stream)
{
    const float* X  = (const float*)d_in[0];
    const int* spc  = (const int*)d_in[1];
    const float* W0 = (const float*)d_in[2];
    const float* b0 = (const float*)d_in[3];
    const float* W1 = (const float*)d_in[4];
    const float* b1 = (const float*)d_in[5];
    const float* W2 = (const float*)d_in[6];
    const float* b2 = (const float*)d_in[7];
    const float* W3 = (const float*)d_in[8];
    const float* b3 = (const float*)d_in[9];
    f16* wp = (f16*)d_ws;
    float* out = (float*)d_out;

    hipMemsetAsync(d_out, 0, (size_t)out_size * sizeof(float), stream);
    pack_weights<<<dim3(512, 4), 256, 0, stream>>>(W0, W1, W2, W3, wp);
    ani_kernel<<<dim3(BMOL / TB, NATOM), 256, 0, stream>>>(X, spc, b0, b1, b2, b3, wp, out);
}

// Round 2
// 681.605 us; speedup vs baseline: 1.0462x; 1.0462x over previous
//
#include <hip/hip_runtime.h>
#include <stdint.h>

// ---------------------------------------------------------------------------
// ANI species-routed MLP, fused, f16 MFMA (gfx950).  Round 2 structure:
//  - Weights read DIRECTLY from packed global (L2-resident) as per-lane 16B
//    fragments -> no weight LDS staging, no per-K-step barriers.
//  - Only 15 barriers/block: 12 for X triple-buffer staging (L0) + 3 layer
//    transitions.  Global W loads are 1-step register-prefetched; barrier
//    drains find them already complete.
//  - Balanced wave->unit mapping: L0 blocked (nt=2w,2w+1 x mi=0,1),
//    L1/L2 strided (mi=w&1, nt=(w>>1)+2i) -> 3 MFMA + 1 LDS read per ks.
// ---------------------------------------------------------------------------

typedef _Float16 f16;
typedef _Float16 f16x8 __attribute__((ext_vector_type(8)));
typedef _Float16 f16x4 __attribute__((ext_vector_type(4)));
typedef float f32x16 __attribute__((ext_vector_type(16)));

static constexpr int NATOM = 256;
static constexpr int BMOL  = 1024;
static constexpr int TB    = 64;

static constexpr size_t PK0 = 0;
static constexpr size_t PK1 = PK0 + 4 * (size_t)98304;   // 393216
static constexpr size_t PK2 = PK1 + 4 * (size_t)49152;   // 589824
static constexpr size_t PK3 = PK2 + 4 * (size_t)36864;   // 737280

// LDS: act0 64x528B, act1 64x400B (xbuf 3x5120B overlays act1 during L0).
static constexpr int S_ACT0   = 528;     // 264 f16, 33 16B-slots (odd -> conflict-free b128)
static constexpr int S_ACT1   = 400;     // 200 f16, 25 slots (odd)
static constexpr int OFF_ACT0 = 0;
static constexpr int OFF_ACT1 = 64 * S_ACT0;            // 33792
static constexpr int OFF_XBUF = OFF_ACT1;               // 3 x 5120 = 15360 <= 25600
static constexpr int SMEM_BYTES = OFF_ACT1 + 64 * S_ACT1; // 59392 -> 2 blocks/CU

__device__ __forceinline__ float celu_f(float x) {
    float e = __expf(x * 10.0f);
    return fmaxf(x, 0.0f) + fminf(0.0f, 0.1f * (e - 1.0f));
}

// ---------------- pack: weights -> MFMA fragment order (constexpr math) ----
template<int K, int Nreal, int NT, int E>
__device__ __forceinline__ void pack_one(const float* __restrict__ W, f16* __restrict__ dst,
                                         int tid, int nth) {
    for (int p = tid; p < 4 * E; p += nth) {
        const int s = p / E, q = p - s * E;
        const int j = q & 7, ll = (q >> 3) & 63, r = q >> 9;
        const int nt = r % NT, ks = r / NT;
        const int k = ks * 16 + ((ll >> 5) << 3) + j;
        const int o = nt * 32 + (ll & 31);
        const float v = (o < Nreal) ? W[((size_t)s * K + k) * Nreal + o] : 0.0f;
        dst[p] = (f16)v;
    }
}

__global__ void pack_weights(const float* __restrict__ W0, const float* __restrict__ W1,
                             const float* __restrict__ W2, const float* __restrict__ W3,
                             f16* __restrict__ wp) {
    const int tid = blockIdx.x * 256 + threadIdx.x, nth = gridDim.x * 256;
    if      (blockIdx.y == 0) pack_one<384, 256, 8, 98304>(W0, wp + PK0, tid, nth);
    else if (blockIdx.y == 1) pack_one<256, 192, 6, 49152>(W1, wp + PK1, tid, nth);
    else if (blockIdx.y == 2) pack_one<192, 160, 6, 36864>(W2, wp + PK2, tid, nth);
    else { for (int p = tid; p < 640; p += nth) wp[PK3 + p] = (f16)W3[p]; }
}

// ---------------- helpers ----------------
__device__ __forceinline__ void loadx8(float* d, const float* p) {
    float4 u = *(const float4*)p;
    float4 v = *(const float4*)(p + 4);
    d[0]=u.x; d[1]=u.y; d[2]=u.z; d[3]=u.w; d[4]=v.x; d[5]=v.y; d[6]=v.z; d[7]=v.w;
}
__device__ __forceinline__ void writex8(char* xb, int row, int kq, const float* v) {
    f16x8 h;
#pragma unroll
    for (int i = 0; i < 8; i++) h[i] = (f16)v[i];
    *(f16x8*)(xb + row * 80 + kq * 2) = h;   // stride 80B = 5 slots (odd)
}

__device__ __forceinline__ f16x8 wfrag(const f16* __restrict__ w, int ks, int NT, int nt, int l) {
    return *(const f16x8*)(w + (((size_t)ks * NT + nt) * 64 + l) * 8);
}

__device__ __forceinline__ void epi_store(const f32x16& a, int nt, int mi, char* actout,
                                          int strideB, const float* __restrict__ bias_sp,
                                          int Nreal, int lo, int hi) {
    if (nt * 32 >= Nreal) return;            // L2's zero-padded cols: no bias read, no store
    const int row = mi * 32 + lo;
#pragma unroll
    for (int q = 0; q < 4; q++) {
        const int o = nt * 32 + q * 8 + hi * 4;
        float4 bv = *(const float4*)(bias_sp + o);
        const float* bp = (const float*)&bv;
        f16x4 hv;
#pragma unroll
        for (int d = 0; d < 4; d++) hv[d] = (f16)celu_f(a[q * 4 + d] + bp[d]);
        *(f16x4*)(actout + row * strideB + o * 2) = hv;
    }
}

// Strided-unit GEMM for NT=6 layers: wave w handles mi=w&1, nt=(w>>1)+{0,2,4}.
template<int KS, int NT>
__device__ __forceinline__ void gemm_str(const char* actin, int sin, const f16* __restrict__ wsrc,
                                         int l, int lo, int hi, int w, f32x16* acc) {
    const int mi = w & 1, nt0 = w >> 1;
    const char* arow = actin + (mi * 32 + lo) * sin + hi * 16;
    f16x8 wf0 = wfrag(wsrc, 0, NT, nt0,     l);
    f16x8 wf1 = wfrag(wsrc, 0, NT, nt0 + 2, l);
    f16x8 wf2 = wfrag(wsrc, 0, NT, nt0 + 4, l);
#pragma unroll
    for (int ks = 0; ks < KS; ks++) {
        f16x8 n0, n1, n2;
        if (ks + 1 < KS) {
            n0 = wfrag(wsrc, ks + 1, NT, nt0,     l);
            n1 = wfrag(wsrc, ks + 1, NT, nt0 + 2, l);
            n2 = wfrag(wsrc, ks + 1, NT, nt0 + 4, l);
        }
        f16x8 af = *(const f16x8*)(arow + ks * 32);
        acc[0] = __builtin_amdgcn_mfma_f32_32x32x16_f16(wf0, af, acc[0], 0, 0, 0);
        acc[1] = __builtin_amdgcn_mfma_f32_32x32x16_f16(wf1, af, acc[1], 0, 0, 0);
        acc[2] = __builtin_amdgcn_mfma_f32_32x32x16_f16(wf2, af, acc[2], 0, 0, 0);
        wf0 = n0; wf1 = n1; wf2 = n2;
    }
}

// ---------------- main fused kernel ----------------
__global__ void __launch_bounds__(256, 2)
ani_kernel(const float* __restrict__ X, const int* __restrict__ species,
           const float* __restrict__ B0, const float* __restrict__ B1,
           const float* __restrict__ B2, const float* __restrict__ B3,
           const f16* __restrict__ wp, float* __restrict__ out)
{
    __shared__ __align__(16) char smem[SMEM_BYTES];
    char* act0 = smem + OFF_ACT0;
    char* act1 = smem + OFF_ACT1;
    char* act2 = smem + OFF_ACT0;   // reuses act0 region
    char* xbuf = smem + OFF_XBUF;   // 3 x 5120, overlays act1 (L0 only)

    const int t = threadIdx.x, l = t & 63, w = t >> 6, lo = l & 31, hi = l >> 5;
    const int atom = blockIdx.y;
    const long brow0 = (long)blockIdx.x * TB;
    const int sp = species[atom];

    f32x16 acc[4];

    // ======== Layer 0: 384 -> 256, X streamed via triple-buffered LDS ========
    {
        const f16* wsrc = wp + PK0 + (size_t)sp * 98304;
        const int xri = t >> 2, kq = (t & 3) * 8;
        const float* xrow = X + ((brow0 + xri) * (long)NATOM + atom) * 384 + kq;

        float xr[2][8];
        loadx8(xr[0], xrow);
        loadx8(xr[1], xrow + 32);
        writex8(xbuf, xri, kq, xr[0]);
        f16x8 wc0 = wfrag(wsrc, 0, 8, 2 * w,     l);
        f16x8 wc1 = wfrag(wsrc, 0, 8, 2 * w + 1, l);
        f16x8 wc2 = wfrag(wsrc, 1, 8, 2 * w,     l);
        f16x8 wc3 = wfrag(wsrc, 1, 8, 2 * w + 1, l);
#pragma unroll
        for (int i = 0; i < 4; i++)
#pragma unroll
            for (int e = 0; e < 16; e++) acc[i][e] = 0.0f;

#pragma unroll
        for (int c = 0; c < 12; c++) {
            // write slab c+1 (regs -> LDS) BEFORE the barrier; readers of that
            // buffer finished before the PREVIOUS barrier (triple buffer).
            if (c + 1 < 12) writex8(xbuf + ((c + 1) % 3) * 5120, xri, kq, xr[(c + 1) & 1]);
            __syncthreads();
            // issue next global loads right after the barrier -> a full slab of
            // compute covers their latency before the next drain.
            if (c + 2 < 12) loadx8(xr[c & 1], xrow + (c + 2) * 32);
            f16x8 wn0, wn1, wn2, wn3;
            if (c + 1 < 12) {
                wn0 = wfrag(wsrc, 2 * c + 2, 8, 2 * w,     l);
                wn1 = wfrag(wsrc, 2 * c + 2, 8, 2 * w + 1, l);
                wn2 = wfrag(wsrc, 2 * c + 3, 8, 2 * w,     l);
                wn3 = wfrag(wsrc, 2 * c + 3, 8, 2 * w + 1, l);
            }
            const char* xb = xbuf + (c % 3) * 5120;
            f16x8 a00 = *(const f16x8*)(xb + lo * 80 + hi * 16);
            f16x8 a01 = *(const f16x8*)(xb + (32 + lo) * 80 + hi * 16);
            acc[0] = __builtin_amdgcn_mfma_f32_32x32x16_f16(wc0, a00, acc[0], 0, 0, 0);
            acc[1] = __builtin_amdgcn_mfma_f32_32x32x16_f16(wc0, a01, acc[1], 0, 0, 0);
            acc[2] = __builtin_amdgcn_mfma_f32_32x32x16_f16(wc1, a00, acc[2], 0, 0, 0);
            acc[3] = __builtin_amdgcn_mfma_f32_32x32x16_f16(wc1, a01, acc[3], 0, 0, 0);
            f16x8 a10 = *(const f16x8*)(xb + lo * 80 + 32 + hi * 16);
            f16x8 a11 = *(const f16x8*)(xb + (32 + lo) * 80 + 32 + hi * 16);
            acc[0] = __builtin_amdgcn_mfma_f32_32x32x16_f16(wc2, a10, acc[0], 0, 0, 0);
            acc[1] = __builtin_amdgcn_mfma_f32_32x32x16_f16(wc2, a11, acc[1], 0, 0, 0);
            acc[2] = __builtin_amdgcn_mfma_f32_32x32x16_f16(wc3, a10, acc[2], 0, 0, 0);
            acc[3] = __builtin_amdgcn_mfma_f32_32x32x16_f16(wc3, a11, acc[3], 0, 0, 0);
            wc0 = wn0; wc1 = wn1; wc2 = wn2; wc3 = wn3;
        }
        const float* bias0 = B0 + sp * 256;
        epi_store(acc[0], 2 * w,     0, act0, S_ACT0, bias0, 256, lo, hi);
        epi_store(acc[1], 2 * w,     1, act0, S_ACT0, bias0, 256, lo, hi);
        epi_store(acc[2], 2 * w + 1, 0, act0, S_ACT0, bias0, 256, lo, hi);
        epi_store(acc[3], 2 * w + 1, 1, act0, S_ACT0, bias0, 256, lo, hi);
        __syncthreads();
    }

    // ======== Layer 1: 256 -> 192 ========
    {
#pragma unroll
        for (int i = 0; i < 3; i++)
#pragma unroll
            for (int e = 0; e < 16; e++) acc[i][e] = 0.0f;
        gemm_str<16, 6>(act0, S_ACT0, wp + PK1 + (size_t)sp * 49152, l, lo, hi, w, acc);
        const float* bias1 = B1 + sp * 192;
        const int nt0 = w >> 1, mi = w & 1;
        epi_store(acc[0], nt0,     mi, act1, S_ACT1, bias1, 192, lo, hi);
        epi_store(acc[1], nt0 + 2, mi, act1, S_ACT1, bias1, 192, lo, hi);
        epi_store(acc[2], nt0 + 4, mi, act1, S_ACT1, bias1, 192, lo, hi);
        __syncthreads();
    }

    // ======== Layer 2: 192 -> 160 (N padded to 192 in weights) ========
    {
#pragma unroll
        for (int i = 0; i < 3; i++)
#pragma unroll
            for (int e = 0; e < 16; e++) acc[i][e] = 0.0f;
        gemm_str<12, 6>(act1, S_ACT1, wp + PK2 + (size_t)sp * 36864, l, lo, hi, w, acc);
        const float* bias2 = B2 + sp * 160;
        const int nt0 = w >> 1, mi = w & 1;
        epi_store(acc[0], nt0,     mi, act2, S_ACT1, bias2, 160, lo, hi);
        epi_store(acc[1], nt0 + 2, mi, act2, S_ACT1, bias2, 160, lo, hi);
        epi_store(acc[2], nt0 + 4, mi, act2, S_ACT1, bias2, 160, lo, hi);
        __syncthreads();
    }

    // ======== Layer 3: 160 -> 1, CELU, pool over atoms ========
    {
        const int row = t >> 2, part = t & 3;
        const char* arow = act2 + row * S_ACT1 + part * 80;
        const f16* wrow = wp + PK3 + sp * 160 + part * 40;
        float sum = 0.0f;
#pragma unroll
        for (int g = 0; g < 5; g++) {
            f16x8 a  = *(const f16x8*)(arow + g * 16);
            f16x8 wv = *(const f16x8*)(wrow + g * 8);
#pragma unroll
            for (int e = 0; e < 8; e++) sum += (float)a[e] * (float)wv[e];
        }
        sum += __shfl_xor(sum, 1, 64);
        sum += __shfl_xor(sum, 2, 64);
        if (part == 0) {
            atomicAdd(out + brow0 + row, celu_f(sum + B3[sp]));
        }
    }
}

// ---------------- launch ----------------
extern "C" void kernel_launch(void* const* d_in, const int* in_sizes, int n_in,
                              void* d_out, int out_size, void* d_ws, size_t ws_size,
                              hipStream_t stream)
{
    const float* X  = (const float*)d_in[0];
    const int* spc  = (const int*)d_in[1];
    const float* W0 = (const float*)d_in[2];
    const float* b0 = (const float*)d_in[3];
    const float* W1 = (const float*)d_in[4];
    const float* b1 = (const float*)d_in[5];
    const float* W2 = (const float*)d_in[6];
    const float* b2 = (const float*)d_in[7];
    const float* W3 = (const float*)d_in[8];
    const float* b3 = (const float*)d_in[9];
    f16* wp = (f16*)d_ws;
    float* out = (float*)d_out;

    hipMemsetAsync(d_out, 0, (size_t)out_size * sizeof(float), stream);
    pack_weights<<<dim3(256, 4), 256, 0, stream>>>(W0, W1, W2, W3, wp);
    ani_kernel<<<dim3(BMOL / TB, NATOM), 256, 0, stream>>>(X, spc, b0, b1, b2, b3, wp, out);
}